// Round 3
// baseline (118.597 us; speedup 1.0000x reference)
//
#include <hip/hip_runtime.h>

// VQVAE quantize.  x: [8,64,32,32] fp32, codebook: [8192,64] fp32.
// d_out (fp32, concat): [0,524288) quant_out | [524288] commit_loss |
//                       [524289] codebook_loss | [524290,532482) indices
//
// argmin via fp16x2 emulated-fp32 MFMA GEMM (3 terms):
//   v = h + m (2 fp16, exact to ~|v|*2^-23); dot ~= hh + hm + mh
//   score = dot - 0.5*e2[k]  (argmax score == argmin d2; absmax 0 R12-R19)
//
// R19 post-mortem: argmin 44.4us, FETCH 9.4MB (3% HBM), L2 1.4TB/s (4%
// of ceiling), MfmaUtil 20, VALUBusy 21, Occupancy 19.7 -> NOT memory-
// bound; latency-bound at 1 block/CU (2 waves/SIMD, 8-wave barrier
// lockstep). R17's "TCC line-service wall" model refuted by counters.
// R20/R21 (R21 = identical resubmit after infra failure): SPLITS 16->32,
// grid (16,32) = 512 blocks = 2 blocks/CU -> 4 waves/SIMD; co-resident
// blocks hide each other's MFMA-latency and barrier tails. 4 chunks of
// 64 codes per block (3 barriers). L2 traffic 64->96MB (irrelevant at
// 4% ceiling). Inner loop unchanged from R19 (depth-2 prefetch, counted
// vmcnt, 3 LDS buffers, e2 staged once, A-frags straight from x).
// R7: B via LDS. R13: 4-tile clusters.

#define N_PTS   8192
#define K_CODES 8192
#define C_DIM   64
#define HWSZ    1024
#define QOUT_N  524288
#define SPLITS  32            // codes per split = 256 = 4 chunks of 64
#define NCH     4             // chunks per split

// ---- workspace layout (bytes) ----
#define WS_PACK  0            // u64 [32][8192]       = 2097152
#define WS_CBS   2097152      // u16 [2*8][8192][8]   = 2097152
#define WS_E2H   4194304      // float [8192]         = 32768
#define WS_PART  4227072      // float [1024]

typedef __attribute__((ext_vector_type(8))) short    short8;
typedef __attribute__((ext_vector_type(8))) _Float16 half8;
typedef __attribute__((ext_vector_type(4))) float    floatx4;

__device__ __forceinline__ half8 as_h8(short8 v) {
    return __builtin_bit_cast(half8, v);
}
__device__ __forceinline__ void split2(float v, unsigned short& h,
                                       unsigned short& m) {
    _Float16 hh = (_Float16)v;                     // RNE
    float r = v - (float)hh;
    _Float16 mm = (_Float16)r;
    h = __builtin_bit_cast(unsigned short, hh);
    m = __builtin_bit_cast(unsigned short, mm);
}
__device__ __forceinline__ void cp16(const void* g, void* l) {
    __builtin_amdgcn_global_load_lds(
        (const __attribute__((address_space(1))) void*)g,
        (__attribute__((address_space(3))) void*)l, 16, 0, 0);
}

// ============================================================
// Kernel A: prep — codebook split + e2 only (32 blocks x 256,
// 1 code row/thread, all writes coalesced 16B).
// Plane layout [p*8+g][k][8], p in {0=h,1=m}: 16B per
// (code, c-octet g) == one MFMA fragment k-group.
// ============================================================
__global__ __launch_bounds__(256)
void vq_prep_kernel(const float* __restrict__ cb,
                    unsigned short* __restrict__ cbS,
                    float* __restrict__ e2h)
{
    const int k = blockIdx.x * 256 + threadIdx.x;
    const float* row = cb + k * C_DIM;
    float s = 0.0f;
    #pragma unroll
    for (int g = 0; g < 8; ++g) {
        float4 a = *(const float4*)(row + g * 8);
        float4 b = *(const float4*)(row + g * 8 + 4);
        float vv[8] = {a.x, a.y, a.z, a.w, b.x, b.y, b.z, b.w};
        unsigned short h8[8], m8[8];
        #pragma unroll
        for (int j = 0; j < 8; ++j) {
            s = fmaf(vv[j], vv[j], s);
            split2(vv[j], h8[j], m8[j]);
        }
        *(uint4*)(cbS + ((size_t)(0 * 8 + g) * 8192 + k) * 8) = *(const uint4*)h8;
        *(uint4*)(cbS + ((size_t)(1 * 8 + g) * 8192 + k) * 8) = *(const uint4*)m8;
    }
    e2h[k] = 0.5f * s;
}

// ============================================================
// Kernel B: argmin via 16x16x32 f16 MFMA. grid (16 m-blocks,
// 32 splits) = 512 blocks x 512 threads (8 waves) = 2 blocks/CU.
// Block tile 512 pts x 256 codes. Wave owns 64 points (4 tiles
// of 16); A-frags built in regs straight from x (64 VGPR).
// Depth-2 prefetch across 3 LDS buffers; per chunk: stage ch+2
// async, compute 4 tiles x 24 MFMA, then counted s_waitcnt
// vmcnt(2) + raw s_barrier (vmcnt(0) only at the last barrier).
// e2 slice (256 floats) staged once in the prologue.
// Final reduce via __shfl_xor u64 min.
// Layouts (verified m89/m91/m120): A[m=lane&15][k=quad*8+j],
// B[k=quad*8+j][n=lane&15], C: col=lane&15, row=quad*4+reg.
// ============================================================
#define SEG_SHORTS 512        // 64 codes * 8 shorts per (p,g) segment
#define NSEGS      16         // 2 planes x 8 octets
#define BUF_SHORTS 8192       // 16*512 (16 KB per buffer)
#define NBUF       3

__device__ __forceinline__ void computeTile(const half8 af[4][2][2],
                                            const unsigned short* __restrict__ bsrc,
                                            const float* __restrict__ se2row,
                                            int tl, int quad, int col, int code,
                                            float bestv[4][4], int besti[4][4])
{
    half8 bf[2][2];
    #pragma unroll
    for (int p = 0; p < 2; ++p)
        #pragma unroll
        for (int s = 0; s < 2; ++s) {
            int seg = p * 8 + s * 4 + quad;
            bf[p][s] = as_h8(*(const short8*)(bsrc + seg * SEG_SHORTS + (tl * 16 + col) * 8));
        }
    float me2 = -se2row[tl * 16 + col];

    floatx4 acc[4];
    #pragma unroll
    for (int t = 0; t < 4; ++t) acc[t] = (floatx4){me2, me2, me2, me2};

    #pragma unroll
    for (int s = 0; s < 2; ++s) {
        #pragma unroll
        for (int t = 0; t < 4; ++t)
            acc[t] = __builtin_amdgcn_mfma_f32_16x16x32_f16(af[t][0][s], bf[0][s], acc[t], 0, 0, 0); // hh
        #pragma unroll
        for (int t = 0; t < 4; ++t)
            acc[t] = __builtin_amdgcn_mfma_f32_16x16x32_f16(af[t][0][s], bf[1][s], acc[t], 0, 0, 0); // hm
        #pragma unroll
        for (int t = 0; t < 4; ++t)
            acc[t] = __builtin_amdgcn_mfma_f32_16x16x32_f16(af[t][1][s], bf[0][s], acc[t], 0, 0, 0); // mh
    }

    #pragma unroll
    for (int t = 0; t < 4; ++t)
        #pragma unroll
        for (int r = 0; r < 4; ++r) {
            float sc = acc[t][r];
            bool gt = sc > bestv[t][r];        // strict: earlier code wins ties
            bestv[t][r] = gt ? sc   : bestv[t][r];
            besti[t][r] = gt ? code : besti[t][r];
        }
}

__global__ __launch_bounds__(512, 1)
void vq_argmin_kernel(const float* __restrict__ x,
                      const unsigned short* __restrict__ cbS,
                      const float* __restrict__ e2h,
                      unsigned long long* __restrict__ packedS)
{
    __shared__ __align__(16) unsigned short sBuf[NBUF][BUF_SHORTS]; // 48 KB
    __shared__ __align__(16) float sE2[256];                        // 1 KB

    const int tid   = threadIdx.x;       // 0..511
    const int lane  = tid & 63;
    const int w     = tid >> 6;          // 0..7
    const int col   = lane & 15;
    const int quad  = lane >> 4;
    const int mb    = blockIdx.x;        // 0..15
    const int split = blockIdx.y;        // 0..31
    const int m0    = mb * 512 + w * 64;
    const int nb0   = split * 256;

    // async stage of one 64-code chunk: 16 segs x 1KB. 512 threads:
    // f = tid + i*512 (i<2); seg = f>>6 wave-uniform, l = f&63 = lane
    // -> wave-uniform LDS base + lane*16 (compliant). Exactly 2
    // global_load_lds per thread per chunk -> uniform vmcnt counting.
    auto stage = [&](int k0, int buf) {
        unsigned short* dst = &sBuf[buf][0];
        #pragma unroll
        for (int i = 0; i < 2; ++i) {
            int f   = tid + i * 512;         // 0..1023
            int seg = f >> 6;
            int l   = f & 63;
            cp16(cbS + ((size_t)seg * 8192 + k0 + l) * 8,
                 dst + seg * SEG_SHORTS + l * 8);
        }
    };

    // prologue: e2 slice (once, wave 0: lane*16 dst) + chunks 0,1;
    // full drain via syncthreads.
    if (tid < 64)
        cp16(e2h + nb0 + tid * 4, &sE2[tid * 4]);
    stage(nb0, 0);
    stage(nb0 + 64, 1);

    // A fragments straight from x: pt = m0 + t*16 + col, channel
    // c = s*32 + quad*8 + j (matches MFMA k = quad*8+j per s-step).
    // Block covers pts [mb*512, mb*512+512) -> single image b = mb>>1.
    const int bimg = mb >> 1;
    const int hwB  = (mb & 1) * 512 + w * 64;
    const float* xb = x + (size_t)bimg * (C_DIM * HWSZ);
    half8 af[4][2][2];
    #pragma unroll
    for (int t = 0; t < 4; ++t) {
        const int hw = hwB + t * 16 + col;
        #pragma unroll
        for (int s = 0; s < 2; ++s) {
            unsigned short h8[8], m8[8];
            #pragma unroll
            for (int j = 0; j < 8; ++j) {
                float v = xb[(size_t)(s * 32 + quad * 8 + j) * HWSZ + hw];
                split2(v, h8[j], m8[j]);
            }
            af[t][0][s] = as_h8(*(const short8*)h8);
            af[t][1][s] = as_h8(*(const short8*)m8);
        }
    }

    float bestv[4][4];
    int   besti[4][4];
    #pragma unroll
    for (int t = 0; t < 4; ++t)
        #pragma unroll
        for (int r = 0; r < 4; ++r) {
            bestv[t][r] = __uint_as_float(0xFF800000u);  // -inf
            besti[t][r] = 0;
        }

    __syncthreads();                     // e2 + chunks 0,1 staged (vmcnt 0)

    // main loop: depth-2 prefetch, counted vmcnt. At iter ch the wave
    // stages ch+2 (2 loads); the epilogue vmcnt(2) retires everything
    // older (in-order), leaving only (ch+2)'s in flight across the
    // barrier. vmcnt(0) only at ch==NCH-2.
    int cbuf = 0, pbuf = 2;
    for (int ch = 0; ch < NCH; ++ch) {
        if (ch < NCH - 2) stage(nb0 + (ch + 2) * 64, pbuf);
        const unsigned short* bsrc = &sBuf[cbuf][0];
        const float* se2row = &sE2[ch * 64];
        #pragma unroll
        for (int tl = 0; tl < 4; ++tl)
            computeTile(af, bsrc, se2row, tl, quad, col,
                        nb0 + ch * 64 + tl * 16 + col, bestv, besti);
        if (ch < NCH - 1) {
            if (ch == NCH - 2) asm volatile("s_waitcnt vmcnt(0)" ::: "memory");
            else               asm volatile("s_waitcnt vmcnt(2)" ::: "memory");
            __builtin_amdgcn_sched_barrier(0);
            __builtin_amdgcn_s_barrier();
            __builtin_amdgcn_sched_barrier(0);
        }
        cbuf = (cbuf == NBUF - 1) ? 0 : cbuf + 1;
        pbuf = (pbuf == NBUF - 1) ? 0 : pbuf + 1;
    }

    // final reduce over the 16 col-candidates per point, in-register:
    // per (t,r), u64-min across the 16 col lanes of each quad group
    // (xor masks 1,2,4,8 stay within the group). Lane with col==t*4+r
    // owns pair (t,r) and writes point m0 + t*16 + quad*4 + r.
    unsigned long long own = 0;
    #pragma unroll
    for (int t = 0; t < 4; ++t)
        #pragma unroll
        for (int r = 0; r < 4; ++r) {
            unsigned u = __float_as_uint(-bestv[t][r]);   // key ascending
            u = ((int)u < 0) ? ~u : (u | 0x80000000u);
            unsigned long long p = ((unsigned long long)u << 32) | (unsigned)besti[t][r];
            #pragma unroll
            for (int msk = 1; msk < 16; msk <<= 1) {
                unsigned long long q = __shfl_xor(p, msk, 64);
                p = (q < p) ? q : p;
            }
            own = (col == t * 4 + r) ? p : own;
        }
    const int mpt = m0 + (col >> 2) * 16 + quad * 4 + (col & 3);
    packedS[(size_t)split * N_PTS + mpt] = own;
}

// ============================================================
// Kernel C: gather. 256 blocks x 256; block owns 32 points,
// 8 threads/point. Phase 1: thread (p=tid&31, sg=tid>>5) reduces
// split slots {sg*4 .. sg*4+3} -> sred[8][32]. Phase 2: every
// thread combines the 8 partials. Phase 3: thread handles
// channels sg*8..sg*8+7, fully coalesced; per-wave loss partials.
// ============================================================
__global__ __launch_bounds__(256)
void vq_gather_kernel(const float* __restrict__ x,
                      const float* __restrict__ cb,
                      const unsigned long long* __restrict__ packedS,
                      float* __restrict__ out,
                      float* __restrict__ part)
{
    __shared__ unsigned long long sred[8][32];
    const int tid = threadIdx.x;
    const int p   = tid & 31;
    const int sg  = tid >> 5;           // 0..7
    const int n0  = blockIdx.x * 32;
    const int n   = n0 + p;

    {
        unsigned long long v = packedS[(size_t)(sg * 4) * N_PTS + n];
        #pragma unroll
        for (int j = 1; j < 4; ++j) {
            unsigned long long q = packedS[(size_t)(sg * 4 + j) * N_PTS + n];
            v = (q < v) ? q : v;
        }
        sred[sg][p] = v;
    }
    __syncthreads();

    unsigned long long v = sred[0][p];
    #pragma unroll
    for (int s = 1; s < 8; ++s) {
        unsigned long long q = sred[s][p];
        v = (q < v) ? q : v;
    }
    const int idx = (int)(v & 0xFFFFFFFFull);
    if (tid < 32) out[QOUT_N + 2 + n0 + tid] = (float)idx;

    const int c0  = sg * 8;
    const int b   = n >> 10;
    const int hw  = n & 1023;
    const float* xb = x   + (size_t)b * (C_DIM * HWSZ) + hw;
    float*       ob = out + (size_t)b * (C_DIM * HWSZ) + hw;

    float s = 0.0f;
    #pragma unroll
    for (int c4 = 0; c4 < 2; ++c4) {
        float4 q = *(const float4*)(cb + (size_t)idx * C_DIM + c0 + c4 * 4);
        float qa[4] = {q.x, q.y, q.z, q.w};
        #pragma unroll
        for (int j = 0; j < 4; ++j) {
            int c = c0 + c4 * 4 + j;
            float xv = xb[c * HWSZ];
            float d  = qa[j] - xv;          // quant - x (reference rounding)
            s = fmaf(d, d, s);
            ob[c * HWSZ] = xv + d;          // straight-through: x + (q - x)
        }
    }

    #pragma unroll
    for (int off = 32; off > 0; off >>= 1) s += __shfl_down(s, off, 64);
    if ((tid & 63) == 0) part[blockIdx.x * 4 + (tid >> 6)] = s;
}

// ============================================================
// Kernel D: final loss reduction (1024 partials -> 2 scalars).
// ============================================================
__global__ __launch_bounds__(256)
void vq_final_kernel(const float* __restrict__ part, float* __restrict__ out)
{
    __shared__ float w[4];
    float s = part[threadIdx.x] + part[threadIdx.x + 256]
            + part[threadIdx.x + 512] + part[threadIdx.x + 768];
    #pragma unroll
    for (int off = 32; off > 0; off >>= 1) s += __shfl_down(s, off, 64);
    if ((threadIdx.x & 63) == 0) w[threadIdx.x >> 6] = s;
    __syncthreads();
    if (threadIdx.x == 0) {
        float m = (w[0] + w[1] + w[2] + w[3]) * (1.0f / (float)QOUT_N);
        out[QOUT_N]     = m;   // commitment_loss
        out[QOUT_N + 1] = m;   // codebook_loss
    }
}

extern "C" void kernel_launch(void* const* d_in, const int* in_sizes, int n_in,
                              void* d_out, int out_size, void* d_ws, size_t ws_size,
                              hipStream_t stream)
{
    const float* x  = (const float*)d_in[0];   // [8,64,32,32]
    const float* cb = (const float*)d_in[1];   // [8192,64]
    float* out = (float*)d_out;
    char*  ws  = (char*)d_ws;
    (void)ws_size;

    unsigned long long* packedS = (unsigned long long*)(ws + WS_PACK);
    unsigned short* cbS = (unsigned short*)(ws + WS_CBS);
    float* e2h = (float*)(ws + WS_E2H);
    float* part = (float*)(ws + WS_PART);

    vq_prep_kernel<<<32, 256, 0, stream>>>(cb, cbS, e2h);
    vq_argmin_kernel<<<dim3(16, SPLITS), 512, 0, stream>>>(x, cbS, e2h, packedS);
    vq_gather_kernel<<<256, 256, 0, stream>>>(x, cb, packedS, out, part);
    vq_final_kernel<<<1, 256, 0, stream>>>(part, out);
}

// Round 4
// 108.196 us; speedup vs baseline: 1.0961x; 1.0961x over previous
//
#include <hip/hip_runtime.h>

// VQVAE quantize.  x: [8,64,32,32] fp32, codebook: [8192,64] fp32.
// d_out (fp32, concat): [0,524288) quant_out | [524288] commit_loss |
//                       [524289] codebook_loss | [524290,532482) indices
//
// argmin via fp16x2 emulated-fp32 MFMA GEMM (3 terms):
//   v = h + m (2 fp16, exact to ~|v|*2^-23); dot ~= hh + hm + mh
//   score = dot - 0.5*e2[k]  (argmax score == argmin d2; absmax 0 R12-R21)
//
// R19: latency-bound at 1 block/CU (MfmaUtil 20, VALUBusy 21, Occ 19.7,
// HBM 3%) -> double blocks/CU. R21 post-mortem: NCH=4 let LLVM fully
// unroll the chunk loop -> VGPR 96->128 + SCRATCH SPILL (WRITE_SIZE
// 1->88 MB = 262k threads x ~340 B; FETCH +43 MB spill reads); scratch
// throttled residency to ~60 blocks (Occ 6.1%) -> 57.6us. The R20
// occupancy experiment never ran.
// R22: same algorithm, unroll(disable) on the chunk loop (R19's rolled
// codegen, runtime cbuf/pbuf). SPLITS=32, grid (16,32)=512 blocks =
// 2 blocks/CU (VGPR<=128, LDS 49KB<=80KB fits). Depth-2 prefetch,
// counted vmcnt(2), 3 LDS buffers, e2 staged once, A-frags from x.
// R7: B via LDS. R13: 4-tile clusters only.

#define N_PTS   8192
#define K_CODES 8192
#define C_DIM   64
#define HWSZ    1024
#define QOUT_N  524288
#define SPLITS  32            // codes per split = 256 = 4 chunks of 64
#define NCH     4             // chunks per split

// ---- workspace layout (bytes) ----
#define WS_PACK  0            // u64 [32][8192]       = 2097152
#define WS_CBS   2097152      // u16 [2*8][8192][8]   = 2097152
#define WS_E2H   4194304      // float [8192]         = 32768
#define WS_PART  4227072      // float [1024]

typedef __attribute__((ext_vector_type(8))) short    short8;
typedef __attribute__((ext_vector_type(8))) _Float16 half8;
typedef __attribute__((ext_vector_type(4))) float    floatx4;

__device__ __forceinline__ half8 as_h8(short8 v) {
    return __builtin_bit_cast(half8, v);
}
__device__ __forceinline__ void split2(float v, unsigned short& h,
                                       unsigned short& m) {
    _Float16 hh = (_Float16)v;                     // RNE
    float r = v - (float)hh;
    _Float16 mm = (_Float16)r;
    h = __builtin_bit_cast(unsigned short, hh);
    m = __builtin_bit_cast(unsigned short, mm);
}
__device__ __forceinline__ void cp16(const void* g, void* l) {
    __builtin_amdgcn_global_load_lds(
        (const __attribute__((address_space(1))) void*)g,
        (__attribute__((address_space(3))) void*)l, 16, 0, 0);
}

// ============================================================
// Kernel A: prep — codebook split + e2 only (32 blocks x 256,
// 1 code row/thread, all writes coalesced 16B).
// Plane layout [p*8+g][k][8], p in {0=h,1=m}: 16B per
// (code, c-octet g) == one MFMA fragment k-group.
// ============================================================
__global__ __launch_bounds__(256)
void vq_prep_kernel(const float* __restrict__ cb,
                    unsigned short* __restrict__ cbS,
                    float* __restrict__ e2h)
{
    const int k = blockIdx.x * 256 + threadIdx.x;
    const float* row = cb + k * C_DIM;
    float s = 0.0f;
    #pragma unroll
    for (int g = 0; g < 8; ++g) {
        float4 a = *(const float4*)(row + g * 8);
        float4 b = *(const float4*)(row + g * 8 + 4);
        float vv[8] = {a.x, a.y, a.z, a.w, b.x, b.y, b.z, b.w};
        unsigned short h8[8], m8[8];
        #pragma unroll
        for (int j = 0; j < 8; ++j) {
            s = fmaf(vv[j], vv[j], s);
            split2(vv[j], h8[j], m8[j]);
        }
        *(uint4*)(cbS + ((size_t)(0 * 8 + g) * 8192 + k) * 8) = *(const uint4*)h8;
        *(uint4*)(cbS + ((size_t)(1 * 8 + g) * 8192 + k) * 8) = *(const uint4*)m8;
    }
    e2h[k] = 0.5f * s;
}

// ============================================================
// Kernel B: argmin via 16x16x32 f16 MFMA. grid (16 m-blocks,
// 32 splits) = 512 blocks x 512 threads (8 waves) = 2 blocks/CU.
// Block tile 512 pts x 256 codes. Wave owns 64 points (4 tiles
// of 16); A-frags built in regs straight from x (64 VGPR).
// Depth-2 prefetch across 3 LDS buffers; per chunk: stage ch+2
// async, compute 4 tiles x 12 MFMA, then counted s_waitcnt
// vmcnt(2) + raw s_barrier (vmcnt(0) only at the last barrier).
// e2 slice (256 floats) staged once in the prologue.
// Chunk loop MUST stay rolled (R21: full unroll -> spill).
// Final reduce via __shfl_xor u64 min.
// Layouts (verified m89/m91/m120): A[m=lane&15][k=quad*8+j],
// B[k=quad*8+j][n=lane&15], C: col=lane&15, row=quad*4+reg.
// ============================================================
#define SEG_SHORTS 512        // 64 codes * 8 shorts per (p,g) segment
#define NSEGS      16         // 2 planes x 8 octets
#define BUF_SHORTS 8192       // 16*512 (16 KB per buffer)
#define NBUF       3

__device__ __forceinline__ void computeTile(const half8 af[4][2][2],
                                            const unsigned short* __restrict__ bsrc,
                                            const float* __restrict__ se2row,
                                            int tl, int quad, int col, int code,
                                            float bestv[4][4], int besti[4][4])
{
    half8 bf[2][2];
    #pragma unroll
    for (int p = 0; p < 2; ++p)
        #pragma unroll
        for (int s = 0; s < 2; ++s) {
            int seg = p * 8 + s * 4 + quad;
            bf[p][s] = as_h8(*(const short8*)(bsrc + seg * SEG_SHORTS + (tl * 16 + col) * 8));
        }
    float me2 = -se2row[tl * 16 + col];

    floatx4 acc[4];
    #pragma unroll
    for (int t = 0; t < 4; ++t) acc[t] = (floatx4){me2, me2, me2, me2};

    #pragma unroll
    for (int s = 0; s < 2; ++s) {
        #pragma unroll
        for (int t = 0; t < 4; ++t)
            acc[t] = __builtin_amdgcn_mfma_f32_16x16x32_f16(af[t][0][s], bf[0][s], acc[t], 0, 0, 0); // hh
        #pragma unroll
        for (int t = 0; t < 4; ++t)
            acc[t] = __builtin_amdgcn_mfma_f32_16x16x32_f16(af[t][0][s], bf[1][s], acc[t], 0, 0, 0); // hm
        #pragma unroll
        for (int t = 0; t < 4; ++t)
            acc[t] = __builtin_amdgcn_mfma_f32_16x16x32_f16(af[t][1][s], bf[0][s], acc[t], 0, 0, 0); // mh
    }

    #pragma unroll
    for (int t = 0; t < 4; ++t)
        #pragma unroll
        for (int r = 0; r < 4; ++r) {
            float sc = acc[t][r];
            bool gt = sc > bestv[t][r];        // strict: earlier code wins ties
            bestv[t][r] = gt ? sc   : bestv[t][r];
            besti[t][r] = gt ? code : besti[t][r];
        }
}

__global__ __launch_bounds__(512, 1)
void vq_argmin_kernel(const float* __restrict__ x,
                      const unsigned short* __restrict__ cbS,
                      const float* __restrict__ e2h,
                      unsigned long long* __restrict__ packedS)
{
    __shared__ __align__(16) unsigned short sBuf[NBUF][BUF_SHORTS]; // 48 KB
    __shared__ __align__(16) float sE2[256];                        // 1 KB

    const int tid   = threadIdx.x;       // 0..511
    const int lane  = tid & 63;
    const int w     = tid >> 6;          // 0..7
    const int col   = lane & 15;
    const int quad  = lane >> 4;
    const int mb    = blockIdx.x;        // 0..15
    const int split = blockIdx.y;        // 0..31
    const int m0    = mb * 512 + w * 64;
    const int nb0   = split * 256;

    // async stage of one 64-code chunk: 16 segs x 1KB. 512 threads:
    // f = tid + i*512 (i<2); seg = f>>6 wave-uniform, l = f&63 = lane
    // -> wave-uniform LDS base + lane*16 (compliant). Exactly 2
    // global_load_lds per thread per chunk -> uniform vmcnt counting.
    auto stage = [&](int k0, int buf) {
        unsigned short* dst = &sBuf[buf][0];
        #pragma unroll
        for (int i = 0; i < 2; ++i) {
            int f   = tid + i * 512;         // 0..1023
            int seg = f >> 6;
            int l   = f & 63;
            cp16(cbS + ((size_t)seg * 8192 + k0 + l) * 8,
                 dst + seg * SEG_SHORTS + l * 8);
        }
    };

    // prologue: e2 slice (once, wave 0: lane*16 dst) + chunks 0,1;
    // full drain via syncthreads.
    if (tid < 64)
        cp16(e2h + nb0 + tid * 4, &sE2[tid * 4]);
    stage(nb0, 0);
    stage(nb0 + 64, 1);

    // A fragments straight from x: pt = m0 + t*16 + col, channel
    // c = s*32 + quad*8 + j (matches MFMA k = quad*8+j per s-step).
    // Block covers pts [mb*512, mb*512+512) -> single image b = mb>>1.
    const int bimg = mb >> 1;
    const int hwB  = (mb & 1) * 512 + w * 64;
    const float* xb = x + (size_t)bimg * (C_DIM * HWSZ);
    half8 af[4][2][2];
    #pragma unroll
    for (int t = 0; t < 4; ++t) {
        const int hw = hwB + t * 16 + col;
        #pragma unroll
        for (int s = 0; s < 2; ++s) {
            unsigned short h8[8], m8[8];
            #pragma unroll
            for (int j = 0; j < 8; ++j) {
                float v = xb[(size_t)(s * 32 + quad * 8 + j) * HWSZ + hw];
                split2(v, h8[j], m8[j]);
            }
            af[t][0][s] = as_h8(*(const short8*)h8);
            af[t][1][s] = as_h8(*(const short8*)m8);
        }
    }

    float bestv[4][4];
    int   besti[4][4];
    #pragma unroll
    for (int t = 0; t < 4; ++t)
        #pragma unroll
        for (int r = 0; r < 4; ++r) {
            bestv[t][r] = __uint_as_float(0xFF800000u);  // -inf
            besti[t][r] = 0;
        }

    __syncthreads();                     // e2 + chunks 0,1 staged (vmcnt 0)

    // main loop: depth-2 prefetch, counted vmcnt. At iter ch the wave
    // stages ch+2 (2 loads); the epilogue vmcnt(2) retires everything
    // older (in-order), leaving only (ch+2)'s in flight across the
    // barrier. vmcnt(0) only at ch==NCH-2.
    // R21 lesson: keep this loop ROLLED — full unroll overlaps chunk
    // live-ranges past the 128-VGPR target and spills to scratch.
    int cbuf = 0, pbuf = 2;
    #pragma clang loop unroll(disable)
    for (int ch = 0; ch < NCH; ++ch) {
        if (ch < NCH - 2) stage(nb0 + (ch + 2) * 64, pbuf);
        const unsigned short* bsrc = &sBuf[cbuf][0];
        const float* se2row = &sE2[ch * 64];
        #pragma unroll
        for (int tl = 0; tl < 4; ++tl)
            computeTile(af, bsrc, se2row, tl, quad, col,
                        nb0 + ch * 64 + tl * 16 + col, bestv, besti);
        if (ch < NCH - 1) {
            if (ch == NCH - 2) asm volatile("s_waitcnt vmcnt(0)" ::: "memory");
            else               asm volatile("s_waitcnt vmcnt(2)" ::: "memory");
            __builtin_amdgcn_sched_barrier(0);
            __builtin_amdgcn_s_barrier();
            __builtin_amdgcn_sched_barrier(0);
        }
        cbuf = (cbuf == NBUF - 1) ? 0 : cbuf + 1;
        pbuf = (pbuf == NBUF - 1) ? 0 : pbuf + 1;
    }

    // final reduce over the 16 col-candidates per point, in-register:
    // per (t,r), u64-min across the 16 col lanes of each quad group
    // (xor masks 1,2,4,8 stay within the group). Lane with col==t*4+r
    // owns pair (t,r) and writes point m0 + t*16 + quad*4 + r.
    unsigned long long own = 0;
    #pragma unroll
    for (int t = 0; t < 4; ++t)
        #pragma unroll
        for (int r = 0; r < 4; ++r) {
            unsigned u = __float_as_uint(-bestv[t][r]);   // key ascending
            u = ((int)u < 0) ? ~u : (u | 0x80000000u);
            unsigned long long p = ((unsigned long long)u << 32) | (unsigned)besti[t][r];
            #pragma unroll
            for (int msk = 1; msk < 16; msk <<= 1) {
                unsigned long long q = __shfl_xor(p, msk, 64);
                p = (q < p) ? q : p;
            }
            own = (col == t * 4 + r) ? p : own;
        }
    const int mpt = m0 + (col >> 2) * 16 + quad * 4 + (col & 3);
    packedS[(size_t)split * N_PTS + mpt] = own;
}

// ============================================================
// Kernel C: gather. 256 blocks x 256; block owns 32 points,
// 8 threads/point. Phase 1: thread (p=tid&31, sg=tid>>5) reduces
// split slots {sg*4 .. sg*4+3} -> sred[8][32]. Phase 2: every
// thread combines the 8 partials. Phase 3: thread handles
// channels sg*8..sg*8+7, fully coalesced; per-wave loss partials.
// ============================================================
__global__ __launch_bounds__(256)
void vq_gather_kernel(const float* __restrict__ x,
                      const float* __restrict__ cb,
                      const unsigned long long* __restrict__ packedS,
                      float* __restrict__ out,
                      float* __restrict__ part)
{
    __shared__ unsigned long long sred[8][32];
    const int tid = threadIdx.x;
    const int p   = tid & 31;
    const int sg  = tid >> 5;           // 0..7
    const int n0  = blockIdx.x * 32;
    const int n   = n0 + p;

    {
        unsigned long long v = packedS[(size_t)(sg * 4) * N_PTS + n];
        #pragma unroll
        for (int j = 1; j < 4; ++j) {
            unsigned long long q = packedS[(size_t)(sg * 4 + j) * N_PTS + n];
            v = (q < v) ? q : v;
        }
        sred[sg][p] = v;
    }
    __syncthreads();

    unsigned long long v = sred[0][p];
    #pragma unroll
    for (int s = 1; s < 8; ++s) {
        unsigned long long q = sred[s][p];
        v = (q < v) ? q : v;
    }
    const int idx = (int)(v & 0xFFFFFFFFull);
    if (tid < 32) out[QOUT_N + 2 + n0 + tid] = (float)idx;

    const int c0  = sg * 8;
    const int b   = n >> 10;
    const int hw  = n & 1023;
    const float* xb = x   + (size_t)b * (C_DIM * HWSZ) + hw;
    float*       ob = out + (size_t)b * (C_DIM * HWSZ) + hw;

    float s = 0.0f;
    #pragma unroll
    for (int c4 = 0; c4 < 2; ++c4) {
        float4 q = *(const float4*)(cb + (size_t)idx * C_DIM + c0 + c4 * 4);
        float qa[4] = {q.x, q.y, q.z, q.w};
        #pragma unroll
        for (int j = 0; j < 4; ++j) {
            int c = c0 + c4 * 4 + j;
            float xv = xb[c * HWSZ];
            float d  = qa[j] - xv;          // quant - x (reference rounding)
            s = fmaf(d, d, s);
            ob[c * HWSZ] = xv + d;          // straight-through: x + (q - x)
        }
    }

    #pragma unroll
    for (int off = 32; off > 0; off >>= 1) s += __shfl_down(s, off, 64);
    if ((tid & 63) == 0) part[blockIdx.x * 4 + (tid >> 6)] = s;
}

// ============================================================
// Kernel D: final loss reduction (1024 partials -> 2 scalars).
// ============================================================
__global__ __launch_bounds__(256)
void vq_final_kernel(const float* __restrict__ part, float* __restrict__ out)
{
    __shared__ float w[4];
    float s = part[threadIdx.x] + part[threadIdx.x + 256]
            + part[threadIdx.x + 512] + part[threadIdx.x + 768];
    #pragma unroll
    for (int off = 32; off > 0; off >>= 1) s += __shfl_down(s, off, 64);
    if ((threadIdx.x & 63) == 0) w[threadIdx.x >> 6] = s;
    __syncthreads();
    if (threadIdx.x == 0) {
        float m = (w[0] + w[1] + w[2] + w[3]) * (1.0f / (float)QOUT_N);
        out[QOUT_N]     = m;   // commitment_loss
        out[QOUT_N + 1] = m;   // codebook_loss
    }
}

extern "C" void kernel_launch(void* const* d_in, const int* in_sizes, int n_in,
                              void* d_out, int out_size, void* d_ws, size_t ws_size,
                              hipStream_t stream)
{
    const float* x  = (const float*)d_in[0];   // [8,64,32,32]
    const float* cb = (const float*)d_in[1];   // [8192,64]
    float* out = (float*)d_out;
    char*  ws  = (char*)d_ws;
    (void)ws_size;

    unsigned long long* packedS = (unsigned long long*)(ws + WS_PACK);
    unsigned short* cbS = (unsigned short*)(ws + WS_CBS);
    float* e2h = (float*)(ws + WS_E2H);
    float* part = (float*)(ws + WS_PART);

    vq_prep_kernel<<<32, 256, 0, stream>>>(cb, cbS, e2h);
    vq_argmin_kernel<<<dim3(16, SPLITS), 512, 0, stream>>>(x, cbS, e2h, packedS);
    vq_gather_kernel<<<256, 256, 0, stream>>>(x, cb, packedS, out, part);
    vq_final_kernel<<<1, 256, 0, stream>>>(part, out);
}

// Round 5
// 98.279 us; speedup vs baseline: 1.2067x; 1.1009x over previous
//
#include <hip/hip_runtime.h>

// VQVAE quantize.  x: [8,64,32,32] fp32, codebook: [8192,64] fp32.
// d_out (fp32, concat): [0,524288) quant_out | [524288] commit_loss |
//                       [524289] codebook_loss | [524290,532482) indices
//
// argmin via fp16x2 emulated-fp32 MFMA GEMM (3 terms):
//   v = h + m (2 fp16, exact to ~|v|*2^-23); dot ~= hh + hm + mh
//   score = dot - 0.5*e2[k]  (argmax score == argmin d2; absmax 0 R12-R22)
//
// R22 post-mortem: occupancy STUCK at 19% with 512 8-wave blocks.
// Cause: combined reg state ~160/wave (VGPR_Count 96 + 64 AGPR-side
// af frags; unified file) -> 3 waves/SIMD cap; an 8-wave block needs
// 2/SIMD, a second needs 4 > 3 -> hard 1 block/CU in R19 AND R22.
// Chunk-cost fit (R19 vs R22): ~5.2us/chunk vs ~0.8us issue cycles ->
// stall-dominated at 2 waves/SIMD; LDS+barrier lockstep amplifies.
// R23: (1) 2 point-tiles/wave -> ~100 combined regs; (2) 4-wave
// 256-thr blocks + __launch_bounds__(256,4) -> >=4 waves/SIMD (50%+);
// (3) NO LDS, NO barriers: B-chunk (16KB) is L1-resident, co-resident
// blocks share the split's codes; read bf/e2 straight from global so
// the compiler pipelines loads freely and waves are independent.
// R21 lesson: chunk loop stays rolled. R13: 4-tile tl clusters only.

#define N_PTS   8192
#define K_CODES 8192
#define C_DIM   64
#define HWSZ    1024
#define QOUT_N  524288
#define SPLITS  32            // codes per split = 256 = 4 chunks of 64
#define NCH     4             // chunks per split

// ---- workspace layout (bytes) ----
#define WS_PACK  0            // u64 [32][8192]       = 2097152
#define WS_CBS   2097152      // u16 [2*8][8192][8]   = 2097152
#define WS_E2H   4194304      // float [8192]         = 32768
#define WS_PART  4227072      // float [1024]

typedef __attribute__((ext_vector_type(8))) short    short8;
typedef __attribute__((ext_vector_type(8))) _Float16 half8;
typedef __attribute__((ext_vector_type(4))) float    floatx4;

__device__ __forceinline__ half8 as_h8(short8 v) {
    return __builtin_bit_cast(half8, v);
}
__device__ __forceinline__ void split2(float v, unsigned short& h,
                                       unsigned short& m) {
    _Float16 hh = (_Float16)v;                     // RNE
    float r = v - (float)hh;
    _Float16 mm = (_Float16)r;
    h = __builtin_bit_cast(unsigned short, hh);
    m = __builtin_bit_cast(unsigned short, mm);
}

// ============================================================
// Kernel A: prep — codebook split + e2 only (32 blocks x 256,
// 1 code row/thread, all writes coalesced 16B).
// Plane layout [p*8+g][k][8], p in {0=h,1=m}: 16B per
// (code, c-octet g) == one MFMA fragment k-group.
// ============================================================
__global__ __launch_bounds__(256)
void vq_prep_kernel(const float* __restrict__ cb,
                    unsigned short* __restrict__ cbS,
                    float* __restrict__ e2h)
{
    const int k = blockIdx.x * 256 + threadIdx.x;
    const float* row = cb + k * C_DIM;
    float s = 0.0f;
    #pragma unroll
    for (int g = 0; g < 8; ++g) {
        float4 a = *(const float4*)(row + g * 8);
        float4 b = *(const float4*)(row + g * 8 + 4);
        float vv[8] = {a.x, a.y, a.z, a.w, b.x, b.y, b.z, b.w};
        unsigned short h8[8], m8[8];
        #pragma unroll
        for (int j = 0; j < 8; ++j) {
            s = fmaf(vv[j], vv[j], s);
            split2(vv[j], h8[j], m8[j]);
        }
        *(uint4*)(cbS + ((size_t)(0 * 8 + g) * 8192 + k) * 8) = *(const uint4*)h8;
        *(uint4*)(cbS + ((size_t)(1 * 8 + g) * 8192 + k) * 8) = *(const uint4*)m8;
    }
    e2h[k] = 0.5f * s;
}

// ============================================================
// Kernel B: argmin via 16x16x32 f16 MFMA. grid (64 m-blocks,
// 32 splits) = 2048 blocks x 256 threads (4 waves). Wave owns
// 32 points (2 tiles of 16) x 256 codes. NO LDS, NO barriers:
// per 16-code tile, bf[2][2] (4x dwordx4) and e2 are read
// straight from global (16KB chunk is L1-resident; co-resident
// blocks share the split). A-frags from x in regs (~32 regs).
// Combined reg state ~100 -> with launch_bounds(256,4) at least
// 4 waves/SIMD co-resident (vs 2 in R19-R22).
// Final reduce via __shfl_xor u64 min (8 owner cols).
// Layouts (verified m89/m91/m120): A[m=lane&15][k=quad*8+j],
// B[k=quad*8+j][n=lane&15], C: col=lane&15, row=quad*4+reg.
// ============================================================
__global__ __launch_bounds__(256, 4)
void vq_argmin_kernel(const float* __restrict__ x,
                      const unsigned short* __restrict__ cbS,
                      const float* __restrict__ e2h,
                      unsigned long long* __restrict__ packedS)
{
    const int tid   = threadIdx.x;       // 0..255
    const int lane  = tid & 63;
    const int w     = tid >> 6;          // 0..3
    const int col   = lane & 15;
    const int quad  = lane >> 4;
    const int mb    = blockIdx.x;        // 0..63
    const int split = blockIdx.y;        // 0..31
    const int m0    = mb * 128 + w * 32;
    const int nb0   = split * 256;

    // A fragments straight from x: pt = m0 + t*16 + col, channel
    // c = s*32 + quad*8 + j (matches MFMA k = quad*8+j per s-step).
    // 128 pts per block never cross an image (1024 pts/image).
    const int bimg = m0 >> 10;
    const int hw0  = m0 & 1023;
    const float* xb = x + (size_t)bimg * (C_DIM * HWSZ);
    half8 af[2][2][2];                   // [tile][plane][s] = 32 regs
    #pragma unroll
    for (int t = 0; t < 2; ++t) {
        const int hw = hw0 + t * 16 + col;
        #pragma unroll
        for (int s = 0; s < 2; ++s) {
            unsigned short h8[8], m8[8];
            #pragma unroll
            for (int j = 0; j < 8; ++j) {
                float v = xb[(size_t)(s * 32 + quad * 8 + j) * HWSZ + hw];
                split2(v, h8[j], m8[j]);
            }
            af[t][0][s] = as_h8(*(const short8*)h8);
            af[t][1][s] = as_h8(*(const short8*)m8);
        }
    }

    float bestv[2][4];
    int   besti[2][4];
    #pragma unroll
    for (int t = 0; t < 2; ++t)
        #pragma unroll
        for (int r = 0; r < 4; ++r) {
            bestv[t][r] = __uint_as_float(0xFF800000u);  // -inf
            besti[t][r] = 0;
        }

    // main loop: 4 chunks x 4 tiles of 16 codes; everything from
    // global (L1). Rolled ch loop (R21: unroll -> spill); tl loop
    // unrolled so the compiler pipelines loads across tiles.
    #pragma clang loop unroll(disable)
    for (int ch = 0; ch < NCH; ++ch) {
        const int k0 = nb0 + ch * 64;
        #pragma unroll
        for (int tl = 0; tl < 4; ++tl) {
            const int code = k0 + tl * 16 + col;
            half8 bf[2][2];
            #pragma unroll
            for (int p = 0; p < 2; ++p)
                #pragma unroll
                for (int s = 0; s < 2; ++s) {
                    int seg = p * 8 + s * 4 + quad;
                    bf[p][s] = as_h8(*(const short8*)(cbS + ((size_t)seg * 8192 + code) * 8));
                }
            float me2 = -e2h[code];

            floatx4 acc[2];
            #pragma unroll
            for (int t = 0; t < 2; ++t) acc[t] = (floatx4){me2, me2, me2, me2};

            #pragma unroll
            for (int s = 0; s < 2; ++s) {
                #pragma unroll
                for (int t = 0; t < 2; ++t)
                    acc[t] = __builtin_amdgcn_mfma_f32_16x16x32_f16(af[t][0][s], bf[0][s], acc[t], 0, 0, 0); // hh
                #pragma unroll
                for (int t = 0; t < 2; ++t)
                    acc[t] = __builtin_amdgcn_mfma_f32_16x16x32_f16(af[t][0][s], bf[1][s], acc[t], 0, 0, 0); // hm
                #pragma unroll
                for (int t = 0; t < 2; ++t)
                    acc[t] = __builtin_amdgcn_mfma_f32_16x16x32_f16(af[t][1][s], bf[0][s], acc[t], 0, 0, 0); // mh
            }

            #pragma unroll
            for (int t = 0; t < 2; ++t)
                #pragma unroll
                for (int r = 0; r < 4; ++r) {
                    float sc = acc[t][r];
                    bool gt = sc > bestv[t][r];    // strict: earlier code wins
                    bestv[t][r] = gt ? sc   : bestv[t][r];
                    besti[t][r] = gt ? code : besti[t][r];
                }
        }
    }

    // final reduce over the 16 col-candidates per point, in-register:
    // per (t,r), u64-min across the 16 col lanes of each quad group
    // (xor masks 1,2,4,8 stay within the group). Lane with col==t*4+r
    // (col 0..7) owns pair (t,r) and writes point m0+t*16+quad*4+r.
    unsigned long long own = 0;
    #pragma unroll
    for (int t = 0; t < 2; ++t)
        #pragma unroll
        for (int r = 0; r < 4; ++r) {
            unsigned u = __float_as_uint(-bestv[t][r]);   // key ascending
            u = ((int)u < 0) ? ~u : (u | 0x80000000u);
            unsigned long long p = ((unsigned long long)u << 32) | (unsigned)besti[t][r];
            #pragma unroll
            for (int msk = 1; msk < 16; msk <<= 1) {
                unsigned long long q = __shfl_xor(p, msk, 64);
                p = (q < p) ? q : p;
            }
            own = (col == t * 4 + r) ? p : own;
        }
    if (col < 8) {
        const int mpt = m0 + (col >> 2) * 16 + quad * 4 + (col & 3);
        packedS[(size_t)split * N_PTS + mpt] = own;
    }
}

// ============================================================
// Kernel C: gather. 256 blocks x 256; block owns 32 points,
// 8 threads/point. Phase 1: thread (p=tid&31, sg=tid>>5) reduces
// split slots {sg*4 .. sg*4+3} -> sred[8][32]. Phase 2: every
// thread combines the 8 partials. Phase 3: thread handles
// channels sg*8..sg*8+7, fully coalesced; per-wave loss partials.
// ============================================================
__global__ __launch_bounds__(256)
void vq_gather_kernel(const float* __restrict__ x,
                      const float* __restrict__ cb,
                      const unsigned long long* __restrict__ packedS,
                      float* __restrict__ out,
                      float* __restrict__ part)
{
    __shared__ unsigned long long sred[8][32];
    const int tid = threadIdx.x;
    const int p   = tid & 31;
    const int sg  = tid >> 5;           // 0..7
    const int n0  = blockIdx.x * 32;
    const int n   = n0 + p;

    {
        unsigned long long v = packedS[(size_t)(sg * 4) * N_PTS + n];
        #pragma unroll
        for (int j = 1; j < 4; ++j) {
            unsigned long long q = packedS[(size_t)(sg * 4 + j) * N_PTS + n];
            v = (q < v) ? q : v;
        }
        sred[sg][p] = v;
    }
    __syncthreads();

    unsigned long long v = sred[0][p];
    #pragma unroll
    for (int s = 1; s < 8; ++s) {
        unsigned long long q = sred[s][p];
        v = (q < v) ? q : v;
    }
    const int idx = (int)(v & 0xFFFFFFFFull);
    if (tid < 32) out[QOUT_N + 2 + n0 + tid] = (float)idx;

    const int c0  = sg * 8;
    const int b   = n >> 10;
    const int hw  = n & 1023;
    const float* xb = x   + (size_t)b * (C_DIM * HWSZ) + hw;
    float*       ob = out + (size_t)b * (C_DIM * HWSZ) + hw;

    float s = 0.0f;
    #pragma unroll
    for (int c4 = 0; c4 < 2; ++c4) {
        float4 q = *(const float4*)(cb + (size_t)idx * C_DIM + c0 + c4 * 4);
        float qa[4] = {q.x, q.y, q.z, q.w};
        #pragma unroll
        for (int j = 0; j < 4; ++j) {
            int c = c0 + c4 * 4 + j;
            float xv = xb[c * HWSZ];
            float d  = qa[j] - xv;          // quant - x (reference rounding)
            s = fmaf(d, d, s);
            ob[c * HWSZ] = xv + d;          // straight-through: x + (q - x)
        }
    }

    #pragma unroll
    for (int off = 32; off > 0; off >>= 1) s += __shfl_down(s, off, 64);
    if ((tid & 63) == 0) part[blockIdx.x * 4 + (tid >> 6)] = s;
}

// ============================================================
// Kernel D: final loss reduction (1024 partials -> 2 scalars).
// ============================================================
__global__ __launch_bounds__(256)
void vq_final_kernel(const float* __restrict__ part, float* __restrict__ out)
{
    __shared__ float w[4];
    float s = part[threadIdx.x] + part[threadIdx.x + 256]
            + part[threadIdx.x + 512] + part[threadIdx.x + 768];
    #pragma unroll
    for (int off = 32; off > 0; off >>= 1) s += __shfl_down(s, off, 64);
    if ((threadIdx.x & 63) == 0) w[threadIdx.x >> 6] = s;
    __syncthreads();
    if (threadIdx.x == 0) {
        float m = (w[0] + w[1] + w[2] + w[3]) * (1.0f / (float)QOUT_N);
        out[QOUT_N]     = m;   // commitment_loss
        out[QOUT_N + 1] = m;   // codebook_loss
    }
}

extern "C" void kernel_launch(void* const* d_in, const int* in_sizes, int n_in,
                              void* d_out, int out_size, void* d_ws, size_t ws_size,
                              hipStream_t stream)
{
    const float* x  = (const float*)d_in[0];   // [8,64,32,32]
    const float* cb = (const float*)d_in[1];   // [8192,64]
    float* out = (float*)d_out;
    char*  ws  = (char*)d_ws;
    (void)ws_size;

    unsigned long long* packedS = (unsigned long long*)(ws + WS_PACK);
    unsigned short* cbS = (unsigned short*)(ws + WS_CBS);
    float* e2h = (float*)(ws + WS_E2H);
    float* part = (float*)(ws + WS_PART);

    vq_prep_kernel<<<32, 256, 0, stream>>>(cb, cbS, e2h);
    vq_argmin_kernel<<<dim3(64, SPLITS), 256, 0, stream>>>(x, cbS, e2h, packedS);
    vq_gather_kernel<<<256, 256, 0, stream>>>(x, cb, packedS, out, part);
    vq_final_kernel<<<1, 256, 0, stream>>>(part, out);
}